// Round 8
// baseline (178.221 us; speedup 1.0000x reference)
//
#include <hip/hip_runtime.h>
#include <hip/hip_bf16.h>

// Fused WindowAttention: x @ W_qkv + b -> MHA(16 heads, D=64) -> @ W_proj + b
// B=8, N=1024, C=1024. fp32 in/out; internal bf16 MFMA + fp32 accum.
//
// Pipeline:
//   1. convert_f32_bf16 : X fp32 -> Xb bf16
//   2. transpose_w x2   : W_qkv -> Wqt [3072][1024] bf16, W_proj -> Wpt bf16
//   3. qkv_gemm4: 256x256 tile, 8 waves, m201-style 4-phase/K-tile schedule
//      (per-phase ds_read||stage||MFMA interleave, counted vmcnt, setprio)
//   4. v_transpose      : V [bh][n][64] -> VtG [bh][64][n]
//   5. attn_kernel v5 (round-6 form)
//   6. proj_gemm2 (m97 structure, round-6 form) -> fp32 d_out

using bf16x8 = __attribute__((ext_vector_type(8))) short;
using f32x4  = __attribute__((ext_vector_type(4))) float;
using u16    = unsigned short;
using u16x4  = __attribute__((ext_vector_type(4))) unsigned short;
using u16x8  = __attribute__((ext_vector_type(8))) unsigned short;
using u32x2  = __attribute__((ext_vector_type(2))) unsigned int;

__device__ __forceinline__ u16 f2bf(float f) {
  unsigned int u = __float_as_uint(f);
  u += 0x7FFFu + ((u >> 16) & 1u);   // RNE (finite inputs only)
  return (u16)(u >> 16);
}
__device__ __forceinline__ float bf2f(u16 h) {
  return __uint_as_float(((unsigned int)h) << 16);
}
__device__ __forceinline__ unsigned cvt_pk_bf16(float a, float b) {
  unsigned r;
  asm("v_cvt_pk_bf16_f32 %0, %1, %2" : "=v"(r) : "v"(a), "v"(b));
  return r;
}
__device__ __forceinline__ float fexp2(float x) {
#if __has_builtin(__builtin_amdgcn_exp2f)
  return __builtin_amdgcn_exp2f(x);
#else
  return exp2f(x);
#endif
}

__device__ __forceinline__ void gload16(const u16* g, u16* lbase, int lane) {
#if __has_builtin(__builtin_amdgcn_global_load_lds)
  __builtin_amdgcn_global_load_lds(
      (const __attribute__((address_space(1))) void*)g,
      (__attribute__((address_space(3))) void*)lbase, 16, 0, 0);
#else
  *(u16x8*)(lbase + (size_t)lane * 8) = *(const u16x8*)g;
#endif
}

// ---------------------------------------------------------------------------
__global__ __launch_bounds__(256) void convert_f32_bf16(
    const float* __restrict__ in, u16* __restrict__ out)
{
  size_t i = ((size_t)blockIdx.x * 256 + threadIdx.x) * 8;
  f32x4 a = *(const f32x4*)(in + i);
  f32x4 b = *(const f32x4*)(in + i + 4);
  u16x8 h = { f2bf(a.x), f2bf(a.y), f2bf(a.z), f2bf(a.w),
              f2bf(b.x), f2bf(b.y), f2bf(b.z), f2bf(b.w) };
  *(u16x8*)(out + i) = h;
}

// ---------------------------------------------------------------------------
__global__ __launch_bounds__(256) void transpose_w(
    const float* __restrict__ W, u16* __restrict__ Wt, int K, int N)
{
  __shared__ float T[64][65];
  const int t = threadIdx.x;
  const int n0 = blockIdx.x * 64, k0 = blockIdx.y * 64;
  const int r = t >> 4, c4 = (t & 15) * 4;
  #pragma unroll
  for (int i = 0; i < 4; ++i) {
    f32x4 v = *(const f32x4*)&W[(size_t)(k0 + r + i * 16) * N + n0 + c4];
    T[r + i * 16][c4 + 0] = v.x;
    T[r + i * 16][c4 + 1] = v.y;
    T[r + i * 16][c4 + 2] = v.z;
    T[r + i * 16][c4 + 3] = v.w;
  }
  __syncthreads();
  const int nr = t >> 2, cs = (t & 3) * 16;
  u16x8 h0, h1;
  #pragma unroll
  for (int j = 0; j < 8; ++j) h0[j] = f2bf(T[cs + j][nr]);
  #pragma unroll
  for (int j = 0; j < 8; ++j) h1[j] = f2bf(T[cs + 8 + j][nr]);
  u16* dst = Wt + (size_t)(n0 + nr) * K + k0 + cs;
  *(u16x8*)dst = h0;
  *(u16x8*)(dst + 8) = h1;
}

// ---------------------------------------------------------------------------
__global__ __launch_bounds__(256) void v_transpose(
    const u16* __restrict__ Vr, u16* __restrict__ Vt)
{
  __shared__ u16 T[64 * 70];
  const int bh = blockIdx.x >> 4, nc = blockIdx.x & 15;
  const int t = threadIdx.x;
  const int r = t >> 2, c = (t & 3) * 16;
  const u16* src = Vr + ((size_t)bh * 1024 + nc * 64 + r) * 64 + c;
  *(u16x8*)&T[r * 70 + c]     = *(const u16x8*)src;
  *(u16x8*)&T[r * 70 + c + 8] = *(const u16x8*)(src + 8);
  __syncthreads();
  const int d = t >> 2, n0 = (t & 3) * 16;
  u16x8 o0, o1;
  #pragma unroll
  for (int j = 0; j < 8; ++j) o0[j] = T[(n0 + j) * 70 + d];
  #pragma unroll
  for (int j = 0; j < 8; ++j) o1[j] = T[(n0 + 8 + j) * 70 + d];
  u16* dst = Vt + ((size_t)bh * 64 + d) * 1024 + nc * 64 + n0;
  *(u16x8*)dst = o0;
  *(u16x8*)(dst + 8) = o1;
}

// ---------------------------------------------------------------------------
// QKV GEMM, m201-style schedule. Xb[8192][1024] @ Wqt[3072][1024]^T + bias.
// 256x256 tile, BK=64, 8 waves (2M x 4N), per-wave 128x64 (8x4 frags).
// LDS: A dbuf 2x[256][64] + B dbuf 2x[256][64] = 128 KiB, XOR-swizzled
// (slot16 ^= row&7) via pre-swizzled global source; reads apply same XOR.
// Per K-tile: 4 phases, each {ds_read frag-pair (+B in ph0) | stage 2 of
// next tile's 8 units | barrier | lgkm(0)+schedbar | setprio 16xMFMA | barrier}.
// vmcnt(2) once per tile (next-tile's first 2 loads stay in flight).
// ---------------------------------------------------------------------------
__global__ __launch_bounds__(512, 1) void qkv_gemm4(
    const u16* __restrict__ Xb, const u16* __restrict__ Wt,
    const float* __restrict__ bias,
    u16* __restrict__ Qb, u16* __restrict__ Kb, u16* __restrict__ Vr)
{
  __shared__ __align__(16) u16 LA[2 * 256 * 64];   // 64 KiB
  __shared__ __align__(16) u16 LB[2 * 256 * 64];   // 64 KiB

  const int tid = threadIdx.x;
  const int lane = tid & 63, wid = tid >> 6;
  const int wm = wid >> 2, wn = wid & 3;
  const int lg = lane >> 4, lc = lane & 15;
  const int row0 = blockIdx.x * 256, col0 = blockIdx.y * 256;

  f32x4 acc[8][4];
  #pragma unroll
  for (int m = 0; m < 8; ++m)
    #pragma unroll
    for (int n = 0; n < 4; ++n) acc[m][n] = (f32x4){0.f, 0.f, 0.f, 0.f};

  // staging: unit = 64 rows x 64 k (8 KB). thread -> row tid>>3, slot tid&7,
  // pre-swizzled slot^(row&7). 8 units/tile: A{0,64,128,192}, B{0,64,128,192}.
  const int srow = tid >> 3;
  const int swz = ((tid & 7) ^ ((tid >> 3) & 7)) * 8;
  const u16* gA = Xb + (size_t)(row0 + srow) * 1024 + swz;
  const u16* gB = Wt + (size_t)(col0 + srow) * 1024 + swz;
  u16* lAw = LA + wid * 512;
  u16* lBw = LB + wid * 512;

  #define STAGE_A(tt, R0) gload16(gA + (size_t)(R0) * 1024 + (tt) * 64, \
                                  lAw + ((tt) & 1) * 16384 + (R0) * 64, lane)
  #define STAGE_B(tt, R0) gload16(gB + (size_t)(R0) * 1024 + (tt) * 64, \
                                  lBw + ((tt) & 1) * 16384 + (R0) * 64, lane)

  // prologue: stage tile 0 (8 units)
  STAGE_A(0, 0); STAGE_A(0, 64); STAGE_A(0, 128); STAGE_A(0, 192);
  STAGE_B(0, 0); STAGE_B(0, 64); STAGE_B(0, 128); STAGE_B(0, 192);

  // read-side swizzled k-slot offsets (elems); row&7 == lc&7 for frag rows
  const int xr = lc & 7;
  const int sl0 = (lg ^ xr) * 8, sl1 = ((4 + lg) ^ xr) * 8;
  const int abase = (wm * 128 + lc) * 64;
  const int bbase = (wn * 64 + lc) * 64;

  bf16x8 b[4][2];

  for (int t = 0; t < 16; ++t) {
    const int cb = (t & 1) * 16384;

    // ---------------- phase 0 ----------------
    if (t + 1 < 16) { STAGE_A(t + 1, 0); STAGE_A(t + 1, 64); }
    if (t + 1 < 16) asm volatile("s_waitcnt vmcnt(2)" ::: "memory");
    else            asm volatile("s_waitcnt vmcnt(0)" ::: "memory");
    __builtin_amdgcn_s_barrier();          // all waves' tile-t loads landed

    bf16x8 a2[2][2];
    #pragma unroll
    for (int fn = 0; fn < 4; ++fn) {
      b[fn][0] = *(const bf16x8*)(LB + cb + bbase + fn * 1024 + sl0);
      b[fn][1] = *(const bf16x8*)(LB + cb + bbase + fn * 1024 + sl1);
    }
    #pragma unroll
    for (int i = 0; i < 2; ++i) {
      a2[i][0] = *(const bf16x8*)(LA + cb + abase + i * 1024 + sl0);
      a2[i][1] = *(const bf16x8*)(LA + cb + abase + i * 1024 + sl1);
    }
    asm volatile("s_waitcnt lgkmcnt(0)" ::: "memory");
    __builtin_amdgcn_sched_barrier(0);
    __builtin_amdgcn_s_setprio(1);
    #pragma unroll
    for (int i = 0; i < 2; ++i)
      #pragma unroll
      for (int fn = 0; fn < 4; ++fn) {
        acc[i][fn] = __builtin_amdgcn_mfma_f32_16x16x32_bf16(a2[i][0], b[fn][0], acc[i][fn], 0, 0, 0);
        acc[i][fn] = __builtin_amdgcn_mfma_f32_16x16x32_bf16(a2[i][1], b[fn][1], acc[i][fn], 0, 0, 0);
      }
    __builtin_amdgcn_s_setprio(0);
    __builtin_amdgcn_s_barrier();

    // ---------------- phases 1..3 ----------------
    #pragma unroll
    for (int p = 1; p < 4; ++p) {
      bf16x8 ap[2][2];
      #pragma unroll
      for (int i = 0; i < 2; ++i) {
        ap[i][0] = *(const bf16x8*)(LA + cb + abase + (2 * p + i) * 1024 + sl0);
        ap[i][1] = *(const bf16x8*)(LA + cb + abase + (2 * p + i) * 1024 + sl1);
      }
      if (t + 1 < 16) {
        if (p == 1)      { STAGE_A(t + 1, 128); STAGE_A(t + 1, 192); }
        else if (p == 2) { STAGE_B(t + 1, 0);   STAGE_B(t + 1, 64);  }
        else             { STAGE_B(t + 1, 128); STAGE_B(t + 1, 192); }
      }
      __builtin_amdgcn_s_barrier();
      asm volatile("s_waitcnt lgkmcnt(0)" ::: "memory");
      __builtin_amdgcn_sched_barrier(0);
      __builtin_amdgcn_s_setprio(1);
      #pragma unroll
      for (int i = 0; i < 2; ++i)
        #pragma unroll
        for (int fn = 0; fn < 4; ++fn) {
          acc[2 * p + i][fn] = __builtin_amdgcn_mfma_f32_16x16x32_bf16(ap[i][0], b[fn][0], acc[2 * p + i][fn], 0, 0, 0);
          acc[2 * p + i][fn] = __builtin_amdgcn_mfma_f32_16x16x32_bf16(ap[i][1], b[fn][1], acc[2 * p + i][fn], 0, 0, 0);
        }
      __builtin_amdgcn_s_setprio(0);
      __builtin_amdgcn_s_barrier();
    }
  }
  #undef STAGE_A
  #undef STAGE_B

  // epilogue: +bias, scatter bf16 to [bh][n][64]; col tile is block-uniform
  const int which = col0 >> 10;
  u16* dst = (which == 0) ? Qb : (which == 1) ? Kb : Vr;
  const int bb = row0 >> 10;
  const int hb = ((col0 & 1023) >> 6) + wn;
  #pragma unroll
  for (int fm = 0; fm < 8; ++fm) {
    const int nn0 = (row0 & 1023) + wm * 128 + fm * 16 + lg * 4;
    #pragma unroll
    for (int fn = 0; fn < 4; ++fn) {
      const int d = fn * 16 + lc;
      const float bv = bias[col0 + wn * 64 + fn * 16 + lc];
      #pragma unroll
      for (int r = 0; r < 4; ++r)
        dst[((size_t)(bb * 16 + hb) * 1024 + nn0 + r) * 64 + d] =
            f2bf(acc[fm][fn][r] + bv);
    }
  }
}

// ---------------------------------------------------------------------------
// Flash attention v5 (round-6 form, unchanged).
// ---------------------------------------------------------------------------
__global__ __launch_bounds__(256, 2) void attn_kernel(
    const u16* __restrict__ Q, const u16* __restrict__ K,
    const u16* __restrict__ Vt, u16* __restrict__ O)
{
  __shared__ __align__(16) u16 Ks[64 * 64];
  __shared__ __align__(16) u16 Vs[64 * 64];
  __shared__ __align__(16) u16 Pl[4 * 32 * 72];

  const int tid = threadIdx.x, lane = tid & 63, wid = tid >> 6;
  const int lg = lane >> 4, lc = lane & 15;
  const int bh = blockIdx.x;
  const int qt = blockIdx.y;
  const size_t base = (size_t)bh * 65536;
  const u16* Qp = Q + base;
  const u16* Kp = K + base;
  const u16* Vp = Vt + base;

  const float QSCALE = 0.125f * 1.44269504f;
  bf16x8 qf[2][2];
  #pragma unroll
  for (int f = 0; f < 2; ++f) {
    const u16* qsrc = Qp + (size_t)(qt * 128 + wid * 32 + f * 16 + lc) * 64 + lg * 8;
    #pragma unroll
    for (int ks = 0; ks < 2; ++ks) {
      u16x8 raw = *(const u16x8*)(qsrc + ks * 32);
      bf16x8 t;
      #pragma unroll
      for (int j = 0; j < 8; ++j) t[j] = (short)f2bf(bf2f(raw[j]) * QSCALE);
      qf[f][ks] = t;
    }
  }

  f32x4 o[2][4];
  #pragma unroll
  for (int f = 0; f < 2; ++f)
    #pragma unroll
    for (int d = 0; d < 4; ++d) o[f][d] = (f32x4){0.f, 0.f, 0.f, 0.f};
  float m_r[2] = {-1e30f, -1e30f};
  float l_r[2] = {0.f, 0.f};

  const int srow  = lane >> 3;
  const int sslot = (lane & 7) ^ srow;
  const u16* gK0 = Kp + (size_t)(wid * 16 + srow) * 64 + sslot * 8;
  const u16* gV0 = Vp + (size_t)(wid * 16 + srow) * 1024 + sslot * 8;
  u16* lK0 = Ks + wid * 1024;
  u16* lV0 = Vs + wid * 1024;

  const int xr = lc & 7;
  const int cof0 = ((0 + lg) ^ xr) * 8;
  const int cof1 = ((4 + lg) ^ xr) * 8;
  const int prow = (wid * 32 + lc) * 72;

  for (int kt = 0; kt < 16; ++kt) {
    gload16(gK0 + kt * 4096, lK0, lane);
    gload16(gK0 + kt * 4096 + 512, lK0 + 512, lane);
    gload16(gV0 + kt * 64, lV0, lane);
    gload16(gV0 + 8192 + kt * 64, lV0 + 512, lane);
    __syncthreads();

    f32x4 s[2][4];
    #pragma unroll
    for (int f = 0; f < 2; ++f)
      #pragma unroll
      for (int kb = 0; kb < 4; ++kb) s[f][kb] = (f32x4){0.f, 0.f, 0.f, 0.f};
    #pragma unroll
    for (int ks = 0; ks < 2; ++ks) {
      const int co = ks ? cof1 : cof0;
      #pragma unroll
      for (int kb = 0; kb < 4; ++kb) {
        bf16x8 kfr = *(const bf16x8*)(Ks + (kb * 16 + lc) * 64 + co);
        s[0][kb] = __builtin_amdgcn_mfma_f32_16x16x32_bf16(kfr, qf[0][ks], s[0][kb], 0, 0, 0);
        s[1][kb] = __builtin_amdgcn_mfma_f32_16x16x32_bf16(kfr, qf[1][ks], s[1][kb], 0, 0, 0);
      }
    }

    #pragma unroll
    for (int f = 0; f < 2; ++f) {
      f32x4 t01, t23;
      #pragma unroll
      for (int c = 0; c < 4; ++c) {
        t01[c] = fmaxf(s[f][0][c], s[f][1][c]);
        t23[c] = fmaxf(s[f][2][c], s[f][3][c]);
      }
      float t = fmaxf(fmaxf(fmaxf(t01[0], t01[1]), fmaxf(t01[2], t01[3])),
                      fmaxf(fmaxf(t23[0], t23[1]), fmaxf(t23[2], t23[3])));
      t = fmaxf(t, __shfl_xor(t, 16));
      t = fmaxf(t, __shfl_xor(t, 32));

      if (!__all((t - m_r[f]) <= 11.5f)) {
        float nm = fmaxf(m_r[f], t);
        float sc = fexp2(m_r[f] - nm);
        m_r[f] = nm;
        l_r[f] *= sc;
        #pragma unroll
        for (int r = 0; r < 4; ++r) {
          float scr = __shfl(sc, lg * 4 + r, 16);
          #pragma unroll
          for (int d = 0; d < 4; ++d) o[f][d][r] *= scr;
        }
      }

      float lsum = 0.f;
      #pragma unroll
      for (int kb = 0; kb < 4; ++kb) {
        f32x4 p;
        #pragma unroll
        for (int c = 0; c < 4; ++c) {
          p[c] = fexp2(s[f][kb][c] - m_r[f]);
          lsum += p[c];
        }
        u32x2 w = { cvt_pk_bf16(p[0], p[1]), cvt_pk_bf16(p[2], p[3]) };
        *(u32x2*)(Pl + prow + f * 1152 + kb * 16 + lg * 4) = w;
      }
      l_r[f] += lsum;
    }

    bf16x8 pa[2][2];
    #pragma unroll
    for (int f = 0; f < 2; ++f)
      #pragma unroll
      for (int ks = 0; ks < 2; ++ks)
        pa[f][ks] = *(const bf16x8*)(Pl + prow + f * 1152 + ks * 32 + lg * 8);
    #pragma unroll
    for (int d = 0; d < 4; ++d) {
      #pragma unroll
      for (int ks = 0; ks < 2; ++ks) {
        const int co = ks ? cof1 : cof0;
        bf16x8 vfr = *(const bf16x8*)(Vs + (d * 16 + lc) * 64 + co);
        o[0][d] = __builtin_amdgcn_mfma_f32_16x16x32_bf16(pa[0][ks], vfr, o[0][d], 0, 0, 0);
        o[1][d] = __builtin_amdgcn_mfma_f32_16x16x32_bf16(pa[1][ks], vfr, o[1][d], 0, 0, 0);
      }
    }
    __syncthreads();
  }

  const int b = bh >> 4, h = bh & 15;
  #pragma unroll
  for (int f = 0; f < 2; ++f) {
    float t = l_r[f];
    t += __shfl_xor(t, 16);
    t += __shfl_xor(t, 32);
    float linv = 1.0f / t;
    #pragma unroll
    for (int r = 0; r < 4; ++r) {
      float li = __shfl(linv, lg * 4 + r, 16);
      int n = qt * 128 + wid * 32 + f * 16 + lg * 4 + r;
      u16* dst = O + ((size_t)b * 1024 + n) * 1024 + h * 64 + lc;
      #pragma unroll
      for (int d = 0; d < 4; ++d) dst[d * 16] = f2bf(o[f][d][r] * li);
    }
  }
}

// ---------------------------------------------------------------------------
// Projection GEMM (m97 structure, round-6 form).
// ---------------------------------------------------------------------------
__global__ __launch_bounds__(256, 2) void proj_gemm2(
    const u16* __restrict__ Ab, const u16* __restrict__ Wt,
    const float* __restrict__ bias, float* __restrict__ Out)
{
  constexpr int KD = 1024, NCOL = 1024;
  __shared__ __align__(16) u16 As[128 * 32];
  __shared__ __align__(16) u16 Bs[128 * 32];

  const int tid = threadIdx.x;
  const int lane = tid & 63, wid = tid >> 6;
  const int wr = wid >> 1, wc = wid & 1;
  const int lg = lane >> 4, lc = lane & 15;
  const int row0 = blockIdx.x * 128, col0 = blockIdx.y * 128;

  f32x4 acc[4][4];
  #pragma unroll
  for (int m = 0; m < 4; ++m)
    #pragma unroll
    for (int n = 0; n < 4; ++n) acc[m][n] = (f32x4){0.f, 0.f, 0.f, 0.f};

  const int l4 = lane >> 2, ls = (lane & 3) * 8;
  const u16* gA0 = Ab + (size_t)(row0 + wid * 16 + l4) * KD + ls;
  const u16* gB0 = Wt + (size_t)(col0 + wid * 16 + l4) * KD + ls;
  u16* lA0 = As + wid * 512;
  u16* lB0 = Bs + wid * 512;

  for (int k0 = 0; k0 < KD; k0 += 32) {
    gload16(gA0 + k0, lA0, lane);
    gload16(gA0 + 64 * KD + k0, lA0 + 2048, lane);
    gload16(gB0 + k0, lB0, lane);
    gload16(gB0 + 64 * KD + k0, lB0 + 2048, lane);
    __syncthreads();

    bf16x8 a[4], b[4];
    #pragma unroll
    for (int m = 0; m < 4; ++m)
      a[m] = *(const bf16x8*)(As + (wr * 64 + m * 16 + lc) * 32 + lg * 8);
    #pragma unroll
    for (int n = 0; n < 4; ++n)
      b[n] = *(const bf16x8*)(Bs + (wc * 64 + n * 16 + lc) * 32 + lg * 8);
    #pragma unroll
    for (int m = 0; m < 4; ++m)
      #pragma unroll
      for (int n = 0; n < 4; ++n)
        acc[m][n] = __builtin_amdgcn_mfma_f32_16x16x32_bf16(a[m], b[n], acc[m][n], 0, 0, 0);
    __syncthreads();
  }

  #pragma unroll
  for (int m = 0; m < 4; ++m) {
    #pragma unroll
    for (int n = 0; n < 4; ++n) {
      #pragma unroll
      for (int r = 0; r < 4; ++r) {
        int gr = row0 + wr * 64 + m * 16 + lg * 4 + r;
        int gc = col0 + wc * 64 + n * 16 + lc;
        Out[(size_t)gr * NCOL + gc] = acc[m][n][r] + bias[gc];
      }
    }
  }
}

// ---------------------------------------------------------------------------
extern "C" void kernel_launch(void* const* d_in, const int* in_sizes, int n_in,
                              void* d_out, int out_size, void* d_ws, size_t ws_size,
                              hipStream_t stream) {
  const float* x     = (const float*)d_in[0];
  const float* W_qkv = (const float*)d_in[1];
  const float* b_qkv = (const float*)d_in[2];
  const float* W_prj = (const float*)d_in[3];
  const float* b_prj = (const float*)d_in[4];
  float* out = (float*)d_out;

  const size_t SEG = (size_t)8192 * 1024;   // 8388608 elems (u16)
  char* ws = (char*)d_ws;                   // needs ~59 MiB
  u16* Xb  = (u16*)ws;                      // dead after qkv
  u16* Ab  = Xb;                            // alias: attn output
  u16* VtG = (u16*)(ws + SEG * 2);          // V^T [bh][64][1024]
  u16* Wqt = (u16*)(ws + SEG * 4);
  u16* Wpt = Wqt + (size_t)3072 * 1024;
  u16* Vr  = (u16*)(ws + 41943040);         // V row-major
  u16* Qb  = (u16*)d_out;                   // d_out as scratch
  u16* Kb  = Qb + SEG;

  convert_f32_bf16<<<4096, 256, 0, stream>>>(x, Xb);
  transpose_w<<<dim3(48, 16), 256, 0, stream>>>(W_qkv, Wqt, 1024, 3072);
  transpose_w<<<dim3(16, 16), 256, 0, stream>>>(W_prj, Wpt, 1024, 1024);
  qkv_gemm4<<<dim3(32, 12), 512, 0, stream>>>(Xb, Wqt, b_qkv, Qb, Kb, Vr);
  v_transpose<<<2048, 256, 0, stream>>>(Vr, VtG);
  attn_kernel<<<dim3(128, 8), 256, 0, stream>>>(Qb, Kb, VtG, Ab);
  proj_gemm2<<<dim3(64, 8), 256, 0, stream>>>(Ab, Wpt, b_prj, out);
}

// Round 9
// 159.652 us; speedup vs baseline: 1.1163x; 1.1163x over previous
//
#include <hip/hip_runtime.h>
#include <hip/hip_bf16.h>

// Fused WindowAttention: x @ W_qkv + b -> MHA(16 heads, D=64) -> @ W_proj + b
// B=8, N=1024, C=1024. fp32 in/out; internal bf16 MFMA + fp32 accum.
//
// Pipeline (4 kernels):
//   1. prep: X f32->bf16  +  W_qkv^T -> Wqt bf16  +  W_proj^T -> Wpt bf16
//   2. qkv_gemm2 (m97 structure) -> Q,K row-major [bh][n][64];
//      V^T [bh][64][n] produced in-epilogue via LDS transpose (coalesced)
//   3. attn_kernel v5 (round-6 form)
//   4. proj_gemm2 (m97 structure) -> fp32 d_out

using bf16x8 = __attribute__((ext_vector_type(8))) short;
using f32x4  = __attribute__((ext_vector_type(4))) float;
using u16    = unsigned short;
using u16x8  = __attribute__((ext_vector_type(8))) unsigned short;
using u32x2  = __attribute__((ext_vector_type(2))) unsigned int;

__device__ __forceinline__ u16 f2bf(float f) {
  unsigned int u = __float_as_uint(f);
  u += 0x7FFFu + ((u >> 16) & 1u);   // RNE (finite inputs only)
  return (u16)(u >> 16);
}
__device__ __forceinline__ float bf2f(u16 h) {
  return __uint_as_float(((unsigned int)h) << 16);
}
__device__ __forceinline__ unsigned cvt_pk_bf16(float a, float b) {
  unsigned r;
  asm("v_cvt_pk_bf16_f32 %0, %1, %2" : "=v"(r) : "v"(a), "v"(b));
  return r;
}
__device__ __forceinline__ float fexp2(float x) {
#if __has_builtin(__builtin_amdgcn_exp2f)
  return __builtin_amdgcn_exp2f(x);
#else
  return exp2f(x);
#endif
}

__device__ __forceinline__ void gload16(const u16* g, u16* lbase, int lane) {
#if __has_builtin(__builtin_amdgcn_global_load_lds)
  __builtin_amdgcn_global_load_lds(
      (const __attribute__((address_space(1))) void*)g,
      (__attribute__((address_space(3))) void*)lbase, 16, 0, 0);
#else
  *(u16x8*)(lbase + (size_t)lane * 8) = *(const u16x8*)g;
#endif
}

// ---------------------------------------------------------------------------
// prep: block-range union of {f32->bf16 convert, W_qkv transpose, W_proj
// transpose}. Grid 5120 blocks x 256.
//   [0,4096)    : convert X (8 elems/thread)
//   [4096,4864) : W_qkv [1024][3072] -> Wqt [3072][1024] bf16 (48x16 tiles)
//   [4864,5120) : W_proj [1024][1024] -> Wpt [1024][1024] bf16 (16x16 tiles)
// ---------------------------------------------------------------------------
__device__ __forceinline__ void transpose_tile(
    const float* __restrict__ W, u16* __restrict__ Wt, int K, int N,
    int n0, int k0, float (*T)[65], int t)
{
  const int r = t >> 4, c4 = (t & 15) * 4;
  #pragma unroll
  for (int i = 0; i < 4; ++i) {
    f32x4 v = *(const f32x4*)&W[(size_t)(k0 + r + i * 16) * N + n0 + c4];
    T[r + i * 16][c4 + 0] = v.x;
    T[r + i * 16][c4 + 1] = v.y;
    T[r + i * 16][c4 + 2] = v.z;
    T[r + i * 16][c4 + 3] = v.w;
  }
  __syncthreads();
  const int nr = t >> 2, cs = (t & 3) * 16;
  u16x8 h0, h1;
  #pragma unroll
  for (int j = 0; j < 8; ++j) h0[j] = f2bf(T[cs + j][nr]);
  #pragma unroll
  for (int j = 0; j < 8; ++j) h1[j] = f2bf(T[cs + 8 + j][nr]);
  u16* dst = Wt + (size_t)(n0 + nr) * K + k0 + cs;
  *(u16x8*)dst = h0;
  *(u16x8*)(dst + 8) = h1;
}

__global__ __launch_bounds__(256) void prep(
    const float* __restrict__ x, u16* __restrict__ Xb,
    const float* __restrict__ Wq, u16* __restrict__ Wqt,
    const float* __restrict__ Wp, u16* __restrict__ Wpt)
{
  __shared__ float T[64][65];
  const int bid = blockIdx.x, t = threadIdx.x;
  if (bid < 4096) {
    size_t i = ((size_t)bid * 256 + t) * 8;
    f32x4 a = *(const f32x4*)(x + i);
    f32x4 b = *(const f32x4*)(x + i + 4);
    u16x8 h = { f2bf(a.x), f2bf(a.y), f2bf(a.z), f2bf(a.w),
                f2bf(b.x), f2bf(b.y), f2bf(b.z), f2bf(b.w) };
    *(u16x8*)(Xb + i) = h;
  } else if (bid < 4864) {
    const int tb = bid - 4096;
    transpose_tile(Wq, Wqt, 1024, 3072, (tb % 48) * 64, (tb / 48) * 64, T, t);
  } else {
    const int tb = bid - 4864;
    transpose_tile(Wp, Wpt, 1024, 1024, (tb % 16) * 64, (tb / 16) * 64, T, t);
  }
}

// ---------------------------------------------------------------------------
// QKV GEMM (m97 structure, proven 70.3us form). Q,K -> [bh][n][64] scalar
// scatter; V tile -> LDS transpose -> coalesced V^T [bh][64][n] stores.
// LDS: union { As[128*32]+Bs[128*32] (main loop, 16KB) | Tv[128*130] (33KB) }.
// ---------------------------------------------------------------------------
__global__ __launch_bounds__(256, 2) void qkv_gemm2(
    const u16* __restrict__ Xb, const u16* __restrict__ Wt,
    const float* __restrict__ bias,
    u16* __restrict__ Qb, u16* __restrict__ Kb, u16* __restrict__ VtG)
{
  constexpr int KD = 1024;
  __shared__ __align__(16) u16 SM[128 * 130];   // 33.3 KB
  u16* As = SM;                // 128*32
  u16* Bs = SM + 4096;         // 128*32
  u16* Tv = SM;                // epilogue transpose buffer (union)

  const int tid = threadIdx.x;
  const int lane = tid & 63, wid = tid >> 6;
  const int wr = wid >> 1, wc = wid & 1;
  const int lg = lane >> 4, lc = lane & 15;
  const int row0 = blockIdx.x * 128, col0 = blockIdx.y * 128;

  f32x4 acc[4][4];
  #pragma unroll
  for (int m = 0; m < 4; ++m)
    #pragma unroll
    for (int n = 0; n < 4; ++n) acc[m][n] = (f32x4){0.f, 0.f, 0.f, 0.f};

  const int l4 = lane >> 2, ls = (lane & 3) * 8;
  const u16* gA0 = Xb + (size_t)(row0 + wid * 16 + l4) * KD + ls;
  const u16* gB0 = Wt + (size_t)(col0 + wid * 16 + l4) * KD + ls;
  u16* lA0 = As + wid * 512;
  u16* lB0 = Bs + wid * 512;

  for (int k0 = 0; k0 < KD; k0 += 32) {
    gload16(gA0 + k0, lA0, lane);
    gload16(gA0 + 64 * KD + k0, lA0 + 2048, lane);
    gload16(gB0 + k0, lB0, lane);
    gload16(gB0 + 64 * KD + k0, lB0 + 2048, lane);
    __syncthreads();

    bf16x8 a[4], b[4];
    #pragma unroll
    for (int m = 0; m < 4; ++m)
      a[m] = *(const bf16x8*)(As + (wr * 64 + m * 16 + lc) * 32 + lg * 8);
    #pragma unroll
    for (int n = 0; n < 4; ++n)
      b[n] = *(const bf16x8*)(Bs + (wc * 64 + n * 16 + lc) * 32 + lg * 8);
    #pragma unroll
    for (int m = 0; m < 4; ++m)
      #pragma unroll
      for (int n = 0; n < 4; ++n)
        acc[m][n] = __builtin_amdgcn_mfma_f32_16x16x32_bf16(a[m], b[n], acc[m][n], 0, 0, 0);
    __syncthreads();
  }

  const int which = col0 >> 10;   // block-uniform: 0=Q, 1=K, 2=V
  if (which == 2) {
    // bias-add + write 128x128 tile to LDS (row = n-row, col = channel)
    #pragma unroll
    for (int m = 0; m < 4; ++m) {
      #pragma unroll
      for (int n = 0; n < 4; ++n) {
        const int col = wc * 64 + n * 16 + lc;
        const float bv = bias[col0 + col];
        const int rrow = wr * 64 + m * 16 + lg * 4;
        #pragma unroll
        for (int r = 0; r < 4; ++r)
          Tv[(rrow + r) * 130 + col] = f2bf(acc[m][n][r] + bv);
      }
    }
    __syncthreads();
    // read columns, store coalesced V^T rows: thread -> (channel c, half)
    const int c = tid >> 1, half = tid & 1;
    const int hh = c >> 6, d = c & 63;
    const int bb = row0 >> 10, nb = row0 & 1023;
    const int hbase = (col0 & 1023) >> 6;
    u16* vdst = VtG + ((size_t)(bb * 16 + hbase + hh) * 64 + d) * 1024
                + nb + half * 64;
    #pragma unroll
    for (int g = 0; g < 8; ++g) {
      u16x8 o;
      #pragma unroll
      for (int j = 0; j < 8; ++j)
        o[j] = Tv[(half * 64 + g * 8 + j) * 130 + c];
      *(u16x8*)(vdst + g * 8) = o;
    }
  } else {
    u16* dst = (which == 0) ? Qb : Kb;
    #pragma unroll
    for (int m = 0; m < 4; ++m) {
      #pragma unroll
      for (int n = 0; n < 4; ++n) {
        const int gc = col0 + wc * 64 + n * 16 + lc;
        const float bv = bias[gc];
        const int ci = gc & 1023, h = ci >> 6, d = ci & 63;
        const int gr0 = row0 + wr * 64 + m * 16 + lg * 4;
        const int bb = gr0 >> 10, nn0 = gr0 & 1023;
        #pragma unroll
        for (int r = 0; r < 4; ++r)
          dst[((size_t)(bb * 16 + h) * 1024 + nn0 + r) * 64 + d] =
              f2bf(acc[m][n][r] + bv);
      }
    }
  }
}

// ---------------------------------------------------------------------------
// Flash attention v5 (round-6 form, unchanged).
// ---------------------------------------------------------------------------
__global__ __launch_bounds__(256, 2) void attn_kernel(
    const u16* __restrict__ Q, const u16* __restrict__ K,
    const u16* __restrict__ Vt, u16* __restrict__ O)
{
  __shared__ __align__(16) u16 Ks[64 * 64];
  __shared__ __align__(16) u16 Vs[64 * 64];
  __shared__ __align__(16) u16 Pl[4 * 32 * 72];

  const int tid = threadIdx.x, lane = tid & 63, wid = tid >> 6;
  const int lg = lane >> 4, lc = lane & 15;
  const int bh = blockIdx.x;
  const int qt = blockIdx.y;
  const size_t base = (size_t)bh * 65536;
  const u16* Qp = Q + base;
  const u16* Kp = K + base;
  const u16* Vp = Vt + base;

  const float QSCALE = 0.125f * 1.44269504f;
  bf16x8 qf[2][2];
  #pragma unroll
  for (int f = 0; f < 2; ++f) {
    const u16* qsrc = Qp + (size_t)(qt * 128 + wid * 32 + f * 16 + lc) * 64 + lg * 8;
    #pragma unroll
    for (int ks = 0; ks < 2; ++ks) {
      u16x8 raw = *(const u16x8*)(qsrc + ks * 32);
      bf16x8 t;
      #pragma unroll
      for (int j = 0; j < 8; ++j) t[j] = (short)f2bf(bf2f(raw[j]) * QSCALE);
      qf[f][ks] = t;
    }
  }

  f32x4 o[2][4];
  #pragma unroll
  for (int f = 0; f < 2; ++f)
    #pragma unroll
    for (int d = 0; d < 4; ++d) o[f][d] = (f32x4){0.f, 0.f, 0.f, 0.f};
  float m_r[2] = {-1e30f, -1e30f};
  float l_r[2] = {0.f, 0.f};

  const int srow  = lane >> 3;
  const int sslot = (lane & 7) ^ srow;
  const u16* gK0 = Kp + (size_t)(wid * 16 + srow) * 64 + sslot * 8;
  const u16* gV0 = Vp + (size_t)(wid * 16 + srow) * 1024 + sslot * 8;
  u16* lK0 = Ks + wid * 1024;
  u16* lV0 = Vs + wid * 1024;

  const int xr = lc & 7;
  const int cof0 = ((0 + lg) ^ xr) * 8;
  const int cof1 = ((4 + lg) ^ xr) * 8;
  const int prow = (wid * 32 + lc) * 72;

  for (int kt = 0; kt < 16; ++kt) {
    gload16(gK0 + kt * 4096, lK0, lane);
    gload16(gK0 + kt * 4096 + 512, lK0 + 512, lane);
    gload16(gV0 + kt * 64, lV0, lane);
    gload16(gV0 + 8192 + kt * 64, lV0 + 512, lane);
    __syncthreads();

    f32x4 s[2][4];
    #pragma unroll
    for (int f = 0; f < 2; ++f)
      #pragma unroll
      for (int kb = 0; kb < 4; ++kb) s[f][kb] = (f32x4){0.f, 0.f, 0.f, 0.f};
    #pragma unroll
    for (int ks = 0; ks < 2; ++ks) {
      const int co = ks ? cof1 : cof0;
      #pragma unroll
      for (int kb = 0; kb < 4; ++kb) {
        bf16x8 kfr = *(const bf16x8*)(Ks + (kb * 16 + lc) * 64 + co);
        s[0][kb] = __builtin_amdgcn_mfma_f32_16x16x32_bf16(kfr, qf[0][ks], s[0][kb], 0, 0, 0);
        s[1][kb] = __builtin_amdgcn_mfma_f32_16x16x32_bf16(kfr, qf[1][ks], s[1][kb], 0, 0, 0);
      }
    }

    #pragma unroll
    for (int f = 0; f < 2; ++f) {
      f32x4 t01, t23;
      #pragma unroll
      for (int c = 0; c < 4; ++c) {
        t01[c] = fmaxf(s[f][0][c], s[f][1][c]);
        t23[c] = fmaxf(s[f][2][c], s[f][3][c]);
      }
      float t = fmaxf(fmaxf(fmaxf(t01[0], t01[1]), fmaxf(t01[2], t01[3])),
                      fmaxf(fmaxf(t23[0], t23[1]), fmaxf(t23[2], t23[3])));
      t = fmaxf(t, __shfl_xor(t, 16));
      t = fmaxf(t, __shfl_xor(t, 32));

      if (!__all((t - m_r[f]) <= 11.5f)) {
        float nm = fmaxf(m_r[f], t);
        float sc = fexp2(m_r[f] - nm);
        m_r[f] = nm;
        l_r[f] *= sc;
        #pragma unroll
        for (int r = 0; r < 4; ++r) {
          float scr = __shfl(sc, lg * 4 + r, 16);
          #pragma unroll
          for (int d = 0; d < 4; ++d) o[f][d][r] *= scr;
        }
      }

      float lsum = 0.f;
      #pragma unroll
      for (int kb = 0; kb < 4; ++kb) {
        f32x4 p;
        #pragma unroll
        for (int c = 0; c < 4; ++c) {
          p[c] = fexp2(s[f][kb][c] - m_r[f]);
          lsum += p[c];
        }
        u32x2 w = { cvt_pk_bf16(p[0], p[1]), cvt_pk_bf16(p[2], p[3]) };
        *(u32x2*)(Pl + prow + f * 1152 + kb * 16 + lg * 4) = w;
      }
      l_r[f] += lsum;
    }

    bf16x8 pa[2][2];
    #pragma unroll
    for (int f = 0; f < 2; ++f)
      #pragma unroll
      for (int ks = 0; ks < 2; ++ks)
        pa[f][ks] = *(const bf16x8*)(Pl + prow + f * 1152 + ks * 32 + lg * 8);
    #pragma unroll
    for (int d = 0; d < 4; ++d) {
      #pragma unroll
      for (int ks = 0; ks < 2; ++ks) {
        const int co = ks ? cof1 : cof0;
        bf16x8 vfr = *(const bf16x8*)(Vs + (d * 16 + lc) * 64 + co);
        o[0][d] = __builtin_amdgcn_mfma_f32_16x16x32_bf16(pa[0][ks], vfr, o[0][d], 0, 0, 0);
        o[1][d] = __builtin_amdgcn_mfma_f32_16x16x32_bf16(pa[1][ks], vfr, o[1][d], 0, 0, 0);
      }
    }
    __syncthreads();
  }

  const int b = bh >> 4, h = bh & 15;
  #pragma unroll
  for (int f = 0; f < 2; ++f) {
    float t = l_r[f];
    t += __shfl_xor(t, 16);
    t += __shfl_xor(t, 32);
    float linv = 1.0f / t;
    #pragma unroll
    for (int r = 0; r < 4; ++r) {
      float li = __shfl(linv, lg * 4 + r, 16);
      int n = qt * 128 + wid * 32 + f * 16 + lg * 4 + r;
      u16* dst = O + ((size_t)b * 1024 + n) * 1024 + h * 64 + lc;
      #pragma unroll
      for (int d = 0; d < 4; ++d) dst[d * 16] = f2bf(o[f][d][r] * li);
    }
  }
}

// ---------------------------------------------------------------------------
// Projection GEMM (m97 structure, round-6 form).
// ---------------------------------------------------------------------------
__global__ __launch_bounds__(256, 2) void proj_gemm2(
    const u16* __restrict__ Ab, const u16* __restrict__ Wt,
    const float* __restrict__ bias, float* __restrict__ Out)
{
  constexpr int KD = 1024, NCOL = 1024;
  __shared__ __align__(16) u16 As[128 * 32];
  __shared__ __align__(16) u16 Bs[128 * 32];

  const int tid = threadIdx.x;
  const int lane = tid & 63, wid = tid >> 6;
  const int wr = wid >> 1, wc = wid & 1;
  const int lg = lane >> 4, lc = lane & 15;
  const int row0 = blockIdx.x * 128, col0 = blockIdx.y * 128;

  f32x4 acc[4][4];
  #pragma unroll
  for (int m = 0; m < 4; ++m)
    #pragma unroll
    for (int n = 0; n < 4; ++n) acc[m][n] = (f32x4){0.f, 0.f, 0.f, 0.f};

  const int l4 = lane >> 2, ls = (lane & 3) * 8;
  const u16* gA0 = Ab + (size_t)(row0 + wid * 16 + l4) * KD + ls;
  const u16* gB0 = Wt + (size_t)(col0 + wid * 16 + l4) * KD + ls;
  u16* lA0 = As + wid * 512;
  u16* lB0 = Bs + wid * 512;

  for (int k0 = 0; k0 < KD; k0 += 32) {
    gload16(gA0 + k0, lA0, lane);
    gload16(gA0 + 64 * KD + k0, lA0 + 2048, lane);
    gload16(gB0 + k0, lB0, lane);
    gload16(gB0 + 64 * KD + k0, lB0 + 2048, lane);
    __syncthreads();

    bf16x8 a[4], b[4];
    #pragma unroll
    for (int m = 0; m < 4; ++m)
      a[m] = *(const bf16x8*)(As + (wr * 64 + m * 16 + lc) * 32 + lg * 8);
    #pragma unroll
    for (int n = 0; n < 4; ++n)
      b[n] = *(const bf16x8*)(Bs + (wc * 64 + n * 16 + lc) * 32 + lg * 8);
    #pragma unroll
    for (int m = 0; m < 4; ++m)
      #pragma unroll
      for (int n = 0; n < 4; ++n)
        acc[m][n] = __builtin_amdgcn_mfma_f32_16x16x32_bf16(a[m], b[n], acc[m][n], 0, 0, 0);
    __syncthreads();
  }

  #pragma unroll
  for (int m = 0; m < 4; ++m) {
    #pragma unroll
    for (int n = 0; n < 4; ++n) {
      #pragma unroll
      for (int r = 0; r < 4; ++r) {
        int gr = row0 + wr * 64 + m * 16 + lg * 4 + r;
        int gc = col0 + wc * 64 + n * 16 + lc;
        Out[(size_t)gr * NCOL + gc] = acc[m][n][r] + bias[gc];
      }
    }
  }
}

// ---------------------------------------------------------------------------
extern "C" void kernel_launch(void* const* d_in, const int* in_sizes, int n_in,
                              void* d_out, int out_size, void* d_ws, size_t ws_size,
                              hipStream_t stream) {
  const float* x     = (const float*)d_in[0];
  const float* W_qkv = (const float*)d_in[1];
  const float* b_qkv = (const float*)d_in[2];
  const float* W_prj = (const float*)d_in[3];
  const float* b_prj = (const float*)d_in[4];
  float* out = (float*)d_out;

  const size_t SEG = (size_t)8192 * 1024;   // 8388608 elems (u16)
  char* ws = (char*)d_ws;                   // needs ~42 MiB
  u16* Xb  = (u16*)ws;                      // dead after qkv
  u16* Ab  = Xb;                            // alias: attn output
  u16* VtG = (u16*)(ws + SEG * 2);          // V^T [bh][64][1024]
  u16* Wqt = (u16*)(ws + SEG * 4);
  u16* Wpt = Wqt + (size_t)3072 * 1024;
  u16* Qb  = (u16*)d_out;                   // d_out as scratch
  u16* Kb  = Qb + SEG;

  prep<<<5120, 256, 0, stream>>>(x, Xb, W_qkv, Wqt, W_prj, Wpt);
  qkv_gemm2<<<dim3(64, 24), 256, 0, stream>>>(Xb, Wqt, b_qkv, Qb, Kb, VtG);
  attn_kernel<<<dim3(128, 8), 256, 0, stream>>>(Qb, Kb, VtG, Ab);
  proj_gemm2<<<dim3(64, 8), 256, 0, stream>>>(Ab, Wpt, b_prj, out);
}

// Round 10
// 158.676 us; speedup vs baseline: 1.1232x; 1.0062x over previous
//
#include <hip/hip_runtime.h>
#include <hip/hip_bf16.h>

// Fused WindowAttention: x @ W_qkv + b -> MHA(16 heads, D=64) -> @ W_proj + b
// B=8, N=1024, C=1024. fp32 in/out; internal bf16 MFMA + fp32 accum.
//
// Pipeline (4 kernels):
//   1. prep: X f32->bf16  +  W_qkv^T -> Wqt bf16  +  W_proj^T -> Wpt bf16
//   2. qkv_gemm2 (m97 2-phase skeleton, BK=64, swizzled LDS) -> Q,K row-major;
//      V^T produced in-epilogue via LDS transpose
//   3. attn_kernel v5 + setprio around MFMA clusters
//   4. proj_gemm2 (same BK=64 swizzled structure) -> fp32 d_out

using bf16x8 = __attribute__((ext_vector_type(8))) short;
using f32x4  = __attribute__((ext_vector_type(4))) float;
using u16    = unsigned short;
using u16x8  = __attribute__((ext_vector_type(8))) unsigned short;
using u32x2  = __attribute__((ext_vector_type(2))) unsigned int;

__device__ __forceinline__ u16 f2bf(float f) {
  unsigned int u = __float_as_uint(f);
  u += 0x7FFFu + ((u >> 16) & 1u);   // RNE (finite inputs only)
  return (u16)(u >> 16);
}
__device__ __forceinline__ float bf2f(u16 h) {
  return __uint_as_float(((unsigned int)h) << 16);
}
__device__ __forceinline__ unsigned cvt_pk_bf16(float a, float b) {
  unsigned r;
  asm("v_cvt_pk_bf16_f32 %0, %1, %2" : "=v"(r) : "v"(a), "v"(b));
  return r;
}
__device__ __forceinline__ float fexp2(float x) {
#if __has_builtin(__builtin_amdgcn_exp2f)
  return __builtin_amdgcn_exp2f(x);
#else
  return exp2f(x);
#endif
}

__device__ __forceinline__ void gload16(const u16* g, u16* lbase, int lane) {
#if __has_builtin(__builtin_amdgcn_global_load_lds)
  __builtin_amdgcn_global_load_lds(
      (const __attribute__((address_space(1))) void*)g,
      (__attribute__((address_space(3))) void*)lbase, 16, 0, 0);
#else
  *(u16x8*)(lbase + (size_t)lane * 8) = *(const u16x8*)g;
#endif
}

// ---------------------------------------------------------------------------
// prep: block-range union (round-9 form).
// ---------------------------------------------------------------------------
__device__ __forceinline__ void transpose_tile(
    const float* __restrict__ W, u16* __restrict__ Wt, int K, int N,
    int n0, int k0, float (*T)[65], int t)
{
  const int r = t >> 4, c4 = (t & 15) * 4;
  #pragma unroll
  for (int i = 0; i < 4; ++i) {
    f32x4 v = *(const f32x4*)&W[(size_t)(k0 + r + i * 16) * N + n0 + c4];
    T[r + i * 16][c4 + 0] = v.x;
    T[r + i * 16][c4 + 1] = v.y;
    T[r + i * 16][c4 + 2] = v.z;
    T[r + i * 16][c4 + 3] = v.w;
  }
  __syncthreads();
  const int nr = t >> 2, cs = (t & 3) * 16;
  u16x8 h0, h1;
  #pragma unroll
  for (int j = 0; j < 8; ++j) h0[j] = f2bf(T[cs + j][nr]);
  #pragma unroll
  for (int j = 0; j < 8; ++j) h1[j] = f2bf(T[cs + 8 + j][nr]);
  u16* dst = Wt + (size_t)(n0 + nr) * K + k0 + cs;
  *(u16x8*)dst = h0;
  *(u16x8*)(dst + 8) = h1;
}

__global__ __launch_bounds__(256) void prep(
    const float* __restrict__ x, u16* __restrict__ Xb,
    const float* __restrict__ Wq, u16* __restrict__ Wqt,
    const float* __restrict__ Wp, u16* __restrict__ Wpt)
{
  __shared__ float T[64][65];
  const int bid = blockIdx.x, t = threadIdx.x;
  if (bid < 4096) {
    size_t i = ((size_t)bid * 256 + t) * 8;
    f32x4 a = *(const f32x4*)(x + i);
    f32x4 b = *(const f32x4*)(x + i + 4);
    u16x8 h = { f2bf(a.x), f2bf(a.y), f2bf(a.z), f2bf(a.w),
                f2bf(b.x), f2bf(b.y), f2bf(b.z), f2bf(b.w) };
    *(u16x8*)(Xb + i) = h;
  } else if (bid < 4864) {
    const int tb = bid - 4096;
    transpose_tile(Wq, Wqt, 1024, 3072, (tb % 48) * 64, (tb / 48) * 64, T, t);
  } else {
    const int tb = bid - 4864;
    transpose_tile(Wp, Wpt, 1024, 1024, (tb % 16) * 64, (tb / 16) * 64, T, t);
  }
}

// ---------------------------------------------------------------------------
// Shared GEMM main loop: 128x128 tile, 4 waves (2x2), BK=64, 16 K-iters.
// LDS [row][64] with 16B-slot XOR swizzle (slot ^= row&7): staged via
// pre-swizzled global source (zero-conflict, proven r7/r8); ds_reads apply
// the same involution -> conflict-free b128 reads.
// Per iter: 8 gload_lds | sync | 2x{8 ds_read + 16 MFMA} | sync.
// ---------------------------------------------------------------------------
#define GEMM64_LOOP(ABASE, BBASE, AS, BS)                                     \
  const int tid = threadIdx.x;                                                \
  const int lane = tid & 63, wid = tid >> 6;                                  \
  const int wr = wid >> 1, wc = wid & 1;                                      \
  const int lg = lane >> 4, lc = lane & 15;                                   \
  const int row0 = blockIdx.x * 128, col0 = blockIdx.y * 128;                 \
  f32x4 acc[4][4];                                                            \
  _Pragma("unroll")                                                           \
  for (int m = 0; m < 4; ++m)                                                 \
    _Pragma("unroll")                                                         \
    for (int n = 0; n < 4; ++n) acc[m][n] = (f32x4){0.f, 0.f, 0.f, 0.f};      \
  /* staging: wave stages rows [wid*32, wid*32+32) of A and of B */           \
  const int srow = lane >> 3;                /* 0..7 */                       \
  const int sslot = (lane & 7) ^ srow;       /* pre-swizzled 16B slot */      \
  const u16* gA = (ABASE) + (size_t)(row0 + wid * 32 + srow) * 1024 + sslot * 8; \
  const u16* gB = (BBASE) + (size_t)(col0 + wid * 32 + srow) * 1024 + sslot * 8; \
  u16* lA = (AS) + wid * 2048;                                                \
  u16* lB = (BS) + wid * 2048;                                                \
  /* read-side swizzled slot offsets: slot = ks*4+lg, xor row&7 = lc&7 */     \
  const int xr = lc & 7;                                                      \
  const int sl0 = ((0 + lg) ^ xr) * 8, sl1 = ((4 + lg) ^ xr) * 8;             \
  const int arow = (wr * 64 + lc) * 64, brow = (wc * 64 + lc) * 64;           \
  for (int k0 = 0; k0 < 1024; k0 += 64) {                                     \
    _Pragma("unroll")                                                         \
    for (int c = 0; c < 4; ++c) {                                             \
      gload16(gA + (size_t)c * 8192 + k0, lA + c * 512, lane);                \
      gload16(gB + (size_t)c * 8192 + k0, lB + c * 512, lane);                \
    }                                                                         \
    __syncthreads();                                                          \
    _Pragma("unroll")                                                         \
    for (int ks = 0; ks < 2; ++ks) {                                          \
      const int sl = ks ? sl1 : sl0;                                          \
      bf16x8 a[4], b[4];                                                      \
      _Pragma("unroll")                                                       \
      for (int m = 0; m < 4; ++m)                                             \
        a[m] = *(const bf16x8*)((AS) + arow + m * 1024 + sl);                 \
      _Pragma("unroll")                                                       \
      for (int n = 0; n < 4; ++n)                                             \
        b[n] = *(const bf16x8*)((BS) + brow + n * 1024 + sl);                 \
      __builtin_amdgcn_s_setprio(1);                                          \
      _Pragma("unroll")                                                       \
      for (int m = 0; m < 4; ++m)                                             \
        _Pragma("unroll")                                                     \
        for (int n = 0; n < 4; ++n)                                           \
          acc[m][n] = __builtin_amdgcn_mfma_f32_16x16x32_bf16(                \
              a[m], b[n], acc[m][n], 0, 0, 0);                                \
      __builtin_amdgcn_s_setprio(0);                                          \
    }                                                                         \
    __syncthreads();                                                          \
  }

// ---------------------------------------------------------------------------
// QKV GEMM. Q,K -> [bh][n][64] scalar scatter; V tile -> LDS transpose ->
// coalesced V^T [bh][64][n]. LDS union {As+Bs 32KB | Tv 33.3KB}.
// ---------------------------------------------------------------------------
__global__ __launch_bounds__(256, 2) void qkv_gemm2(
    const u16* __restrict__ Xb, const u16* __restrict__ Wt,
    const float* __restrict__ bias,
    u16* __restrict__ Qb, u16* __restrict__ Kb, u16* __restrict__ VtG)
{
  __shared__ __align__(16) u16 SM[128 * 130];   // 33.3 KB
  u16* As = SM;                // 128*64
  u16* Bs = SM + 8192;         // 128*64
  u16* Tv = SM;                // epilogue transpose buffer (union)

  GEMM64_LOOP(Xb, Wt, As, Bs)

  const int which = col0 >> 10;   // block-uniform: 0=Q, 1=K, 2=V
  if (which == 2) {
    #pragma unroll
    for (int m = 0; m < 4; ++m) {
      #pragma unroll
      for (int n = 0; n < 4; ++n) {
        const int col = wc * 64 + n * 16 + lc;
        const float bv = bias[col0 + col];
        const int rrow = wr * 64 + m * 16 + lg * 4;
        #pragma unroll
        for (int r = 0; r < 4; ++r)
          Tv[(rrow + r) * 130 + col] = f2bf(acc[m][n][r] + bv);
      }
    }
    __syncthreads();
    const int c = tid >> 1, half = tid & 1;
    const int hh = c >> 6, d = c & 63;
    const int bb = row0 >> 10, nb = row0 & 1023;
    const int hbase = (col0 & 1023) >> 6;
    u16* vdst = VtG + ((size_t)(bb * 16 + hbase + hh) * 64 + d) * 1024
                + nb + half * 64;
    #pragma unroll
    for (int g = 0; g < 8; ++g) {
      u16x8 o;
      #pragma unroll
      for (int j = 0; j < 8; ++j)
        o[j] = Tv[(half * 64 + g * 8 + j) * 130 + c];
      *(u16x8*)(vdst + g * 8) = o;
    }
  } else {
    u16* dst = (which == 0) ? Qb : Kb;
    #pragma unroll
    for (int m = 0; m < 4; ++m) {
      #pragma unroll
      for (int n = 0; n < 4; ++n) {
        const int gc = col0 + wc * 64 + n * 16 + lc;
        const float bv = bias[gc];
        const int ci = gc & 1023, h = ci >> 6, d = ci & 63;
        const int gr0 = row0 + wr * 64 + m * 16 + lg * 4;
        const int bb = gr0 >> 10, nn0 = gr0 & 1023;
        #pragma unroll
        for (int r = 0; r < 4; ++r)
          dst[((size_t)(bb * 16 + h) * 1024 + nn0 + r) * 64 + d] =
              f2bf(acc[m][n][r] + bv);
      }
    }
  }
}

// ---------------------------------------------------------------------------
// Flash attention v5 + setprio (T5) around MFMA clusters.
// ---------------------------------------------------------------------------
__global__ __launch_bounds__(256, 2) void attn_kernel(
    const u16* __restrict__ Q, const u16* __restrict__ K,
    const u16* __restrict__ Vt, u16* __restrict__ O)
{
  __shared__ __align__(16) u16 Ks[64 * 64];
  __shared__ __align__(16) u16 Vs[64 * 64];
  __shared__ __align__(16) u16 Pl[4 * 32 * 72];

  const int tid = threadIdx.x, lane = tid & 63, wid = tid >> 6;
  const int lg = lane >> 4, lc = lane & 15;
  const int bh = blockIdx.x;
  const int qt = blockIdx.y;
  const size_t base = (size_t)bh * 65536;
  const u16* Qp = Q + base;
  const u16* Kp = K + base;
  const u16* Vp = Vt + base;

  const float QSCALE = 0.125f * 1.44269504f;
  bf16x8 qf[2][2];
  #pragma unroll
  for (int f = 0; f < 2; ++f) {
    const u16* qsrc = Qp + (size_t)(qt * 128 + wid * 32 + f * 16 + lc) * 64 + lg * 8;
    #pragma unroll
    for (int ks = 0; ks < 2; ++ks) {
      u16x8 raw = *(const u16x8*)(qsrc + ks * 32);
      bf16x8 t;
      #pragma unroll
      for (int j = 0; j < 8; ++j) t[j] = (short)f2bf(bf2f(raw[j]) * QSCALE);
      qf[f][ks] = t;
    }
  }

  f32x4 o[2][4];
  #pragma unroll
  for (int f = 0; f < 2; ++f)
    #pragma unroll
    for (int d = 0; d < 4; ++d) o[f][d] = (f32x4){0.f, 0.f, 0.f, 0.f};
  float m_r[2] = {-1e30f, -1e30f};
  float l_r[2] = {0.f, 0.f};

  const int srow  = lane >> 3;
  const int sslot = (lane & 7) ^ srow;
  const u16* gK0 = Kp + (size_t)(wid * 16 + srow) * 64 + sslot * 8;
  const u16* gV0 = Vp + (size_t)(wid * 16 + srow) * 1024 + sslot * 8;
  u16* lK0 = Ks + wid * 1024;
  u16* lV0 = Vs + wid * 1024;

  const int xr = lc & 7;
  const int cof0 = ((0 + lg) ^ xr) * 8;
  const int cof1 = ((4 + lg) ^ xr) * 8;
  const int prow = (wid * 32 + lc) * 72;

  for (int kt = 0; kt < 16; ++kt) {
    gload16(gK0 + kt * 4096, lK0, lane);
    gload16(gK0 + kt * 4096 + 512, lK0 + 512, lane);
    gload16(gV0 + kt * 64, lV0, lane);
    gload16(gV0 + 8192 + kt * 64, lV0 + 512, lane);
    __syncthreads();

    f32x4 s[2][4];
    #pragma unroll
    for (int f = 0; f < 2; ++f)
      #pragma unroll
      for (int kb = 0; kb < 4; ++kb) s[f][kb] = (f32x4){0.f, 0.f, 0.f, 0.f};
    __builtin_amdgcn_s_setprio(1);
    #pragma unroll
    for (int ks = 0; ks < 2; ++ks) {
      const int co = ks ? cof1 : cof0;
      #pragma unroll
      for (int kb = 0; kb < 4; ++kb) {
        bf16x8 kfr = *(const bf16x8*)(Ks + (kb * 16 + lc) * 64 + co);
        s[0][kb] = __builtin_amdgcn_mfma_f32_16x16x32_bf16(kfr, qf[0][ks], s[0][kb], 0, 0, 0);
        s[1][kb] = __builtin_amdgcn_mfma_f32_16x16x32_bf16(kfr, qf[1][ks], s[1][kb], 0, 0, 0);
      }
    }
    __builtin_amdgcn_s_setprio(0);

    #pragma unroll
    for (int f = 0; f < 2; ++f) {
      f32x4 t01, t23;
      #pragma unroll
      for (int c = 0; c < 4; ++c) {
        t01[c] = fmaxf(s[f][0][c], s[f][1][c]);
        t23[c] = fmaxf(s[f][2][c], s[f][3][c]);
      }
      float t = fmaxf(fmaxf(fmaxf(t01[0], t01[1]), fmaxf(t01[2], t01[3])),
                      fmaxf(fmaxf(t23[0], t23[1]), fmaxf(t23[2], t23[3])));
      t = fmaxf(t, __shfl_xor(t, 16));
      t = fmaxf(t, __shfl_xor(t, 32));

      if (!__all((t - m_r[f]) <= 11.5f)) {
        float nm = fmaxf(m_r[f], t);
        float sc = fexp2(m_r[f] - nm);
        m_r[f] = nm;
        l_r[f] *= sc;
        #pragma unroll
        for (int r = 0; r < 4; ++r) {
          float scr = __shfl(sc, lg * 4 + r, 16);
          #pragma unroll
          for (int d = 0; d < 4; ++d) o[f][d][r] *= scr;
        }
      }

      float lsum = 0.f;
      #pragma unroll
      for (int kb = 0; kb < 4; ++kb) {
        f32x4 p;
        #pragma unroll
        for (int c = 0; c < 4; ++c) {
          p[c] = fexp2(s[f][kb][c] - m_r[f]);
          lsum += p[c];
        }
        u32x2 w = { cvt_pk_bf16(p[0], p[1]), cvt_pk_bf16(p[2], p[3]) };
        *(u32x2*)(Pl + prow + f * 1152 + kb * 16 + lg * 4) = w;
      }
      l_r[f] += lsum;
    }

    bf16x8 pa[2][2];
    #pragma unroll
    for (int f = 0; f < 2; ++f)
      #pragma unroll
      for (int ks = 0; ks < 2; ++ks)
        pa[f][ks] = *(const bf16x8*)(Pl + prow + f * 1152 + ks * 32 + lg * 8);
    __builtin_amdgcn_s_setprio(1);
    #pragma unroll
    for (int d = 0; d < 4; ++d) {
      #pragma unroll
      for (int ks = 0; ks < 2; ++ks) {
        const int co = ks ? cof1 : cof0;
        bf16x8 vfr = *(const bf16x8*)(Vs + (d * 16 + lc) * 64 + co);
        o[0][d] = __builtin_amdgcn_mfma_f32_16x16x32_bf16(pa[0][ks], vfr, o[0][d], 0, 0, 0);
        o[1][d] = __builtin_amdgcn_mfma_f32_16x16x32_bf16(pa[1][ks], vfr, o[1][d], 0, 0, 0);
      }
    }
    __builtin_amdgcn_s_setprio(0);
    __syncthreads();
  }

  const int b = bh >> 4, h = bh & 15;
  #pragma unroll
  for (int f = 0; f < 2; ++f) {
    float t = l_r[f];
    t += __shfl_xor(t, 16);
    t += __shfl_xor(t, 32);
    float linv = 1.0f / t;
    #pragma unroll
    for (int r = 0; r < 4; ++r) {
      float li = __shfl(linv, lg * 4 + r, 16);
      int n = qt * 128 + wid * 32 + f * 16 + lg * 4 + r;
      u16* dst = O + ((size_t)b * 1024 + n) * 1024 + h * 64 + lc;
      #pragma unroll
      for (int d = 0; d < 4; ++d) dst[d * 16] = f2bf(o[f][d][r] * li);
    }
  }
}

// ---------------------------------------------------------------------------
// Projection GEMM (BK=64 swizzled structure).
// ---------------------------------------------------------------------------
__global__ __launch_bounds__(256, 2) void proj_gemm2(
    const u16* __restrict__ Ab, const u16* __restrict__ Wt,
    const float* __restrict__ bias, float* __restrict__ Out)
{
  __shared__ __align__(16) u16 As[128 * 64];
  __shared__ __align__(16) u16 Bs[128 * 64];

  GEMM64_LOOP(Ab, Wt, As, Bs)

  #pragma unroll
  for (int m = 0; m < 4; ++m) {
    #pragma unroll
    for (int n = 0; n < 4; ++n) {
      #pragma unroll
      for (int r = 0; r < 4; ++r) {
        int gr = row0 + wr * 64 + m * 16 + lg * 4 + r;
        int gc = col0 + wc * 64 + n * 16 + lc;
        Out[(size_t)gr * 1024 + gc] = acc[m][n][r] + bias[gc];
      }
    }
  }
}

// ---------------------------------------------------------------------------
extern "C" void kernel_launch(void* const* d_in, const int* in_sizes, int n_in,
                              void* d_out, int out_size, void* d_ws, size_t ws_size,
                              hipStream_t stream) {
  const float* x     = (const float*)d_in[0];
  const float* W_qkv = (const float*)d_in[1];
  const float* b_qkv = (const float*)d_in[2];
  const float* W_prj = (const float*)d_in[3];
  const float* b_prj = (const float*)d_in[4];
  float* out = (float*)d_out;

  const size_t SEG = (size_t)8192 * 1024;   // 8388608 elems (u16)
  char* ws = (char*)d_ws;                   // needs ~42 MiB
  u16* Xb  = (u16*)ws;                      // dead after qkv
  u16* Ab  = Xb;                            // alias: attn output
  u16* VtG = (u16*)(ws + SEG * 2);          // V^T [bh][64][1024]
  u16* Wqt = (u16*)(ws + SEG * 4);
  u16* Wpt = Wqt + (size_t)3072 * 1024;
  u16* Qb  = (u16*)d_out;                   // d_out as scratch
  u16* Kb  = Qb + SEG;

  prep<<<5120, 256, 0, stream>>>(x, Xb, W_qkv, Wqt, W_prj, Wpt);
  qkv_gemm2<<<dim3(64, 24), 256, 0, stream>>>(Xb, Wqt, b_qkv, Qb, Kb, VtG);
  attn_kernel<<<dim3(128, 8), 256, 0, stream>>>(Qb, Kb, VtG, Ab);
  proj_gemm2<<<dim3(64, 8), 256, 0, stream>>>(Ab, Wpt, b_prj, out);
}

// Round 11
// 149.987 us; speedup vs baseline: 1.1882x; 1.0579x over previous
//
#include <hip/hip_runtime.h>
#include <hip/hip_bf16.h>

// Fused WindowAttention: x @ W_qkv + b -> MHA(16 heads, D=64) -> @ W_proj + b
// B=8, N=1024, C=1024. fp32 in/out; internal bf16 MFMA + fp32 accum.
//
// Pipeline (4 kernels):
//   1. prep: X f32->bf16  +  W_qkv^T -> Wqt bf16  +  W_proj^T -> Wpt bf16
//   2. qkv_gemm2 (2-phase, BK=64, swizzled LDS) -> Q,K row-major;
//      V^T produced in-epilogue via LDS transpose
//   3. attn_kernel v5 (NO setprio — it starved the VALU-bound softmax path)
//   4. proj_gemm2 (BK=64 swizzled structure) -> fp32 d_out

using bf16x8 = __attribute__((ext_vector_type(8))) short;
using f32x4  = __attribute__((ext_vector_type(4))) float;
using u16    = unsigned short;
using u16x8  = __attribute__((ext_vector_type(8))) unsigned short;
using u32x2  = __attribute__((ext_vector_type(2))) unsigned int;

__device__ __forceinline__ u16 f2bf(float f) {
  unsigned int u = __float_as_uint(f);
  u += 0x7FFFu + ((u >> 16) & 1u);   // RNE (finite inputs only)
  return (u16)(u >> 16);
}
__device__ __forceinline__ float bf2f(u16 h) {
  return __uint_as_float(((unsigned int)h) << 16);
}
__device__ __forceinline__ unsigned cvt_pk_bf16(float a, float b) {
  unsigned r;
  asm("v_cvt_pk_bf16_f32 %0, %1, %2" : "=v"(r) : "v"(a), "v"(b));
  return r;
}
__device__ __forceinline__ float fexp2(float x) {
#if __has_builtin(__builtin_amdgcn_exp2f)
  return __builtin_amdgcn_exp2f(x);
#else
  return exp2f(x);
#endif
}

__device__ __forceinline__ void gload16(const u16* g, u16* lbase, int lane) {
#if __has_builtin(__builtin_amdgcn_global_load_lds)
  __builtin_amdgcn_global_load_lds(
      (const __attribute__((address_space(1))) void*)g,
      (__attribute__((address_space(3))) void*)lbase, 16, 0, 0);
#else
  *(u16x8*)(lbase + (size_t)lane * 8) = *(const u16x8*)g;
#endif
}

// ---------------------------------------------------------------------------
// prep: block-range union {f32->bf16 convert, W_qkv^T, W_proj^T}.
// ---------------------------------------------------------------------------
__device__ __forceinline__ void transpose_tile(
    const float* __restrict__ W, u16* __restrict__ Wt, int K, int N,
    int n0, int k0, float (*T)[65], int t)
{
  const int r = t >> 4, c4 = (t & 15) * 4;
  #pragma unroll
  for (int i = 0; i < 4; ++i) {
    f32x4 v = *(const f32x4*)&W[(size_t)(k0 + r + i * 16) * N + n0 + c4];
    T[r + i * 16][c4 + 0] = v.x;
    T[r + i * 16][c4 + 1] = v.y;
    T[r + i * 16][c4 + 2] = v.z;
    T[r + i * 16][c4 + 3] = v.w;
  }
  __syncthreads();
  const int nr = t >> 2, cs = (t & 3) * 16;
  u16x8 h0, h1;
  #pragma unroll
  for (int j = 0; j < 8; ++j) h0[j] = f2bf(T[cs + j][nr]);
  #pragma unroll
  for (int j = 0; j < 8; ++j) h1[j] = f2bf(T[cs + 8 + j][nr]);
  u16* dst = Wt + (size_t)(n0 + nr) * K + k0 + cs;
  *(u16x8*)dst = h0;
  *(u16x8*)(dst + 8) = h1;
}

__global__ __launch_bounds__(256) void prep(
    const float* __restrict__ x, u16* __restrict__ Xb,
    const float* __restrict__ Wq, u16* __restrict__ Wqt,
    const float* __restrict__ Wp, u16* __restrict__ Wpt)
{
  __shared__ float T[64][65];
  const int bid = blockIdx.x, t = threadIdx.x;
  if (bid < 4096) {
    size_t i = ((size_t)bid * 256 + t) * 8;
    f32x4 a = *(const f32x4*)(x + i);
    f32x4 b = *(const f32x4*)(x + i + 4);
    u16x8 h = { f2bf(a.x), f2bf(a.y), f2bf(a.z), f2bf(a.w),
                f2bf(b.x), f2bf(b.y), f2bf(b.z), f2bf(b.w) };
    *(u16x8*)(Xb + i) = h;
  } else if (bid < 4864) {
    const int tb = bid - 4096;
    transpose_tile(Wq, Wqt, 1024, 3072, (tb % 48) * 64, (tb / 48) * 64, T, t);
  } else {
    const int tb = bid - 4864;
    transpose_tile(Wp, Wpt, 1024, 1024, (tb % 16) * 64, (tb / 16) * 64, T, t);
  }
}

// ---------------------------------------------------------------------------
// Shared GEMM main loop: 128x128 tile, 4 waves (2x2), BK=64, 16 K-iters.
// LDS [row][64] with 16B-slot XOR swizzle (slot ^= row&7), staged via
// pre-swizzled global source; ds_reads apply the same involution.
// ---------------------------------------------------------------------------
#define GEMM64_LOOP(ABASE, BBASE, AS, BS)                                     \
  const int tid = threadIdx.x;                                                \
  const int lane = tid & 63, wid = tid >> 6;                                  \
  const int wr = wid >> 1, wc = wid & 1;                                      \
  const int lg = lane >> 4, lc = lane & 15;                                   \
  const int row0 = blockIdx.x * 128, col0 = blockIdx.y * 128;                 \
  f32x4 acc[4][4];                                                            \
  _Pragma("unroll")                                                           \
  for (int m = 0; m < 4; ++m)                                                 \
    _Pragma("unroll")                                                         \
    for (int n = 0; n < 4; ++n) acc[m][n] = (f32x4){0.f, 0.f, 0.f, 0.f};      \
  const int srow = lane >> 3;                /* 0..7 */                       \
  const int sslot = (lane & 7) ^ srow;       /* pre-swizzled 16B slot */      \
  const u16* gA = (ABASE) + (size_t)(row0 + wid * 32 + srow) * 1024 + sslot * 8; \
  const u16* gB = (BBASE) + (size_t)(col0 + wid * 32 + srow) * 1024 + sslot * 8; \
  u16* lA = (AS) + wid * 2048;                                                \
  u16* lB = (BS) + wid * 2048;                                                \
  const int xr = lc & 7;                                                      \
  const int sl0 = ((0 + lg) ^ xr) * 8, sl1 = ((4 + lg) ^ xr) * 8;             \
  const int arow = (wr * 64 + lc) * 64, brow = (wc * 64 + lc) * 64;           \
  for (int k0 = 0; k0 < 1024; k0 += 64) {                                     \
    _Pragma("unroll")                                                         \
    for (int c = 0; c < 4; ++c) {                                             \
      gload16(gA + (size_t)c * 8192 + k0, lA + c * 512, lane);                \
      gload16(gB + (size_t)c * 8192 + k0, lB + c * 512, lane);                \
    }                                                                         \
    __syncthreads();                                                          \
    _Pragma("unroll")                                                         \
    for (int ks = 0; ks < 2; ++ks) {                                          \
      const int sl = ks ? sl1 : sl0;                                          \
      bf16x8 a[4], b[4];                                                      \
      _Pragma("unroll")                                                       \
      for (int m = 0; m < 4; ++m)                                             \
        a[m] = *(const bf16x8*)((AS) + arow + m * 1024 + sl);                 \
      _Pragma("unroll")                                                       \
      for (int n = 0; n < 4; ++n)                                             \
        b[n] = *(const bf16x8*)((BS) + brow + n * 1024 + sl);                 \
      __builtin_amdgcn_s_setprio(1);                                          \
      _Pragma("unroll")                                                       \
      for (int m = 0; m < 4; ++m)                                             \
        _Pragma("unroll")                                                     \
        for (int n = 0; n < 4; ++n)                                           \
          acc[m][n] = __builtin_amdgcn_mfma_f32_16x16x32_bf16(                \
              a[m], b[n], acc[m][n], 0, 0, 0);                                \
      __builtin_amdgcn_s_setprio(0);                                          \
    }                                                                         \
    __syncthreads();                                                          \
  }

// ---------------------------------------------------------------------------
// QKV GEMM. Q,K -> [bh][n][64] scalar scatter; V tile -> LDS transpose ->
// coalesced V^T [bh][64][n]. LDS union {As+Bs 32KB | Tv 33.3KB}.
// ---------------------------------------------------------------------------
__global__ __launch_bounds__(256, 2) void qkv_gemm2(
    const u16* __restrict__ Xb, const u16* __restrict__ Wt,
    const float* __restrict__ bias,
    u16* __restrict__ Qb, u16* __restrict__ Kb, u16* __restrict__ VtG)
{
  __shared__ __align__(16) u16 SM[128 * 130];   // 33.3 KB
  u16* As = SM;                // 128*64
  u16* Bs = SM + 8192;         // 128*64
  u16* Tv = SM;                // epilogue transpose buffer (union)

  GEMM64_LOOP(Xb, Wt, As, Bs)

  const int which = col0 >> 10;   // block-uniform: 0=Q, 1=K, 2=V
  if (which == 2) {
    #pragma unroll
    for (int m = 0; m < 4; ++m) {
      #pragma unroll
      for (int n = 0; n < 4; ++n) {
        const int col = wc * 64 + n * 16 + lc;
        const float bv = bias[col0 + col];
        const int rrow = wr * 64 + m * 16 + lg * 4;
        #pragma unroll
        for (int r = 0; r < 4; ++r)
          Tv[(rrow + r) * 130 + col] = f2bf(acc[m][n][r] + bv);
      }
    }
    __syncthreads();
    const int c = tid >> 1, half = tid & 1;
    const int hh = c >> 6, d = c & 63;
    const int bb = row0 >> 10, nb = row0 & 1023;
    const int hbase = (col0 & 1023) >> 6;
    u16* vdst = VtG + ((size_t)(bb * 16 + hbase + hh) * 64 + d) * 1024
                + nb + half * 64;
    #pragma unroll
    for (int g = 0; g < 8; ++g) {
      u16x8 o;
      #pragma unroll
      for (int j = 0; j < 8; ++j)
        o[j] = Tv[(half * 64 + g * 8 + j) * 130 + c];
      *(u16x8*)(vdst + g * 8) = o;
    }
  } else {
    u16* dst = (which == 0) ? Qb : Kb;
    #pragma unroll
    for (int m = 0; m < 4; ++m) {
      #pragma unroll
      for (int n = 0; n < 4; ++n) {
        const int gc = col0 + wc * 64 + n * 16 + lc;
        const float bv = bias[gc];
        const int ci = gc & 1023, h = ci >> 6, d = ci & 63;
        const int gr0 = row0 + wr * 64 + m * 16 + lg * 4;
        const int bb = gr0 >> 10, nn0 = gr0 & 1023;
        #pragma unroll
        for (int r = 0; r < 4; ++r)
          dst[((size_t)(bb * 16 + h) * 1024 + nn0 + r) * 64 + d] =
              f2bf(acc[m][n][r] + bv);
      }
    }
  }
}

// ---------------------------------------------------------------------------
// Flash attention v5 (round-9 form: NO setprio).
// ---------------------------------------------------------------------------
__global__ __launch_bounds__(256, 2) void attn_kernel(
    const u16* __restrict__ Q, const u16* __restrict__ K,
    const u16* __restrict__ Vt, u16* __restrict__ O)
{
  __shared__ __align__(16) u16 Ks[64 * 64];
  __shared__ __align__(16) u16 Vs[64 * 64];
  __shared__ __align__(16) u16 Pl[4 * 32 * 72];

  const int tid = threadIdx.x, lane = tid & 63, wid = tid >> 6;
  const int lg = lane >> 4, lc = lane & 15;
  const int bh = blockIdx.x;
  const int qt = blockIdx.y;
  const size_t base = (size_t)bh * 65536;
  const u16* Qp = Q + base;
  const u16* Kp = K + base;
  const u16* Vp = Vt + base;

  const float QSCALE = 0.125f * 1.44269504f;
  bf16x8 qf[2][2];
  #pragma unroll
  for (int f = 0; f < 2; ++f) {
    const u16* qsrc = Qp + (size_t)(qt * 128 + wid * 32 + f * 16 + lc) * 64 + lg * 8;
    #pragma unroll
    for (int ks = 0; ks < 2; ++ks) {
      u16x8 raw = *(const u16x8*)(qsrc + ks * 32);
      bf16x8 t;
      #pragma unroll
      for (int j = 0; j < 8; ++j) t[j] = (short)f2bf(bf2f(raw[j]) * QSCALE);
      qf[f][ks] = t;
    }
  }

  f32x4 o[2][4];
  #pragma unroll
  for (int f = 0; f < 2; ++f)
    #pragma unroll
    for (int d = 0; d < 4; ++d) o[f][d] = (f32x4){0.f, 0.f, 0.f, 0.f};
  float m_r[2] = {-1e30f, -1e30f};
  float l_r[2] = {0.f, 0.f};

  const int srow  = lane >> 3;
  const int sslot = (lane & 7) ^ srow;
  const u16* gK0 = Kp + (size_t)(wid * 16 + srow) * 64 + sslot * 8;
  const u16* gV0 = Vp + (size_t)(wid * 16 + srow) * 1024 + sslot * 8;
  u16* lK0 = Ks + wid * 1024;
  u16* lV0 = Vs + wid * 1024;

  const int xr = lc & 7;
  const int cof0 = ((0 + lg) ^ xr) * 8;
  const int cof1 = ((4 + lg) ^ xr) * 8;
  const int prow = (wid * 32 + lc) * 72;

  for (int kt = 0; kt < 16; ++kt) {
    gload16(gK0 + kt * 4096, lK0, lane);
    gload16(gK0 + kt * 4096 + 512, lK0 + 512, lane);
    gload16(gV0 + kt * 64, lV0, lane);
    gload16(gV0 + 8192 + kt * 64, lV0 + 512, lane);
    __syncthreads();

    f32x4 s[2][4];
    #pragma unroll
    for (int f = 0; f < 2; ++f)
      #pragma unroll
      for (int kb = 0; kb < 4; ++kb) s[f][kb] = (f32x4){0.f, 0.f, 0.f, 0.f};
    #pragma unroll
    for (int ks = 0; ks < 2; ++ks) {
      const int co = ks ? cof1 : cof0;
      #pragma unroll
      for (int kb = 0; kb < 4; ++kb) {
        bf16x8 kfr = *(const bf16x8*)(Ks + (kb * 16 + lc) * 64 + co);
        s[0][kb] = __builtin_amdgcn_mfma_f32_16x16x32_bf16(kfr, qf[0][ks], s[0][kb], 0, 0, 0);
        s[1][kb] = __builtin_amdgcn_mfma_f32_16x16x32_bf16(kfr, qf[1][ks], s[1][kb], 0, 0, 0);
      }
    }

    #pragma unroll
    for (int f = 0; f < 2; ++f) {
      f32x4 t01, t23;
      #pragma unroll
      for (int c = 0; c < 4; ++c) {
        t01[c] = fmaxf(s[f][0][c], s[f][1][c]);
        t23[c] = fmaxf(s[f][2][c], s[f][3][c]);
      }
      float t = fmaxf(fmaxf(fmaxf(t01[0], t01[1]), fmaxf(t01[2], t01[3])),
                      fmaxf(fmaxf(t23[0], t23[1]), fmaxf(t23[2], t23[3])));
      t = fmaxf(t, __shfl_xor(t, 16));
      t = fmaxf(t, __shfl_xor(t, 32));

      if (!__all((t - m_r[f]) <= 11.5f)) {
        float nm = fmaxf(m_r[f], t);
        float sc = fexp2(m_r[f] - nm);
        m_r[f] = nm;
        l_r[f] *= sc;
        #pragma unroll
        for (int r = 0; r < 4; ++r) {
          float scr = __shfl(sc, lg * 4 + r, 16);
          #pragma unroll
          for (int d = 0; d < 4; ++d) o[f][d][r] *= scr;
        }
      }

      float lsum = 0.f;
      #pragma unroll
      for (int kb = 0; kb < 4; ++kb) {
        f32x4 p;
        #pragma unroll
        for (int c = 0; c < 4; ++c) {
          p[c] = fexp2(s[f][kb][c] - m_r[f]);
          lsum += p[c];
        }
        u32x2 w = { cvt_pk_bf16(p[0], p[1]), cvt_pk_bf16(p[2], p[3]) };
        *(u32x2*)(Pl + prow + f * 1152 + kb * 16 + lg * 4) = w;
      }
      l_r[f] += lsum;
    }

    bf16x8 pa[2][2];
    #pragma unroll
    for (int f = 0; f < 2; ++f)
      #pragma unroll
      for (int ks = 0; ks < 2; ++ks)
        pa[f][ks] = *(const bf16x8*)(Pl + prow + f * 1152 + ks * 32 + lg * 8);
    #pragma unroll
    for (int d = 0; d < 4; ++d) {
      #pragma unroll
      for (int ks = 0; ks < 2; ++ks) {
        const int co = ks ? cof1 : cof0;
        bf16x8 vfr = *(const bf16x8*)(Vs + (d * 16 + lc) * 64 + co);
        o[0][d] = __builtin_amdgcn_mfma_f32_16x16x32_bf16(pa[0][ks], vfr, o[0][d], 0, 0, 0);
        o[1][d] = __builtin_amdgcn_mfma_f32_16x16x32_bf16(pa[1][ks], vfr, o[1][d], 0, 0, 0);
      }
    }
    __syncthreads();
  }

  const int b = bh >> 4, h = bh & 15;
  #pragma unroll
  for (int f = 0; f < 2; ++f) {
    float t = l_r[f];
    t += __shfl_xor(t, 16);
    t += __shfl_xor(t, 32);
    float linv = 1.0f / t;
    #pragma unroll
    for (int r = 0; r < 4; ++r) {
      float li = __shfl(linv, lg * 4 + r, 16);
      int n = qt * 128 + wid * 32 + f * 16 + lg * 4 + r;
      u16* dst = O + ((size_t)b * 1024 + n) * 1024 + h * 64 + lc;
      #pragma unroll
      for (int d = 0; d < 4; ++d) dst[d * 16] = f2bf(o[f][d][r] * li);
    }
  }
}

// ---------------------------------------------------------------------------
// Projection GEMM (BK=64 swizzled structure).
// ---------------------------------------------------------------------------
__global__ __launch_bounds__(256, 2) void proj_gemm2(
    const u16* __restrict__ Ab, const u16* __restrict__ Wt,
    const float* __restrict__ bias, float* __restrict__ Out)
{
  __shared__ __align__(16) u16 As[128 * 64];
  __shared__ __align__(16) u16 Bs[128 * 64];

  GEMM64_LOOP(Ab, Wt, As, Bs)

  #pragma unroll
  for (int m = 0; m < 4; ++m) {
    #pragma unroll
    for (int n = 0; n < 4; ++n) {
      #pragma unroll
      for (int r = 0; r < 4; ++r) {
        int gr = row0 + wr * 64 + m * 16 + lg * 4 + r;
        int gc = col0 + wc * 64 + n * 16 + lc;
        Out[(size_t)gr * 1024 + gc] = acc[m][n][r] + bias[gc];
      }
    }
  }
}

// ---------------------------------------------------------------------------
extern "C" void kernel_launch(void* const* d_in, const int* in_sizes, int n_in,
                              void* d_out, int out_size, void* d_ws, size_t ws_size,
                              hipStream_t stream) {
  const float* x     = (const float*)d_in[0];
  const float* W_qkv = (const float*)d_in[1];
  const float* b_qkv = (const float*)d_in[2];
  const float* W_prj = (const float*)d_in[3];
  const float* b_prj = (const float*)d_in[4];
  float* out = (float*)d_out;

  const size_t SEG = (size_t)8192 * 1024;   // 8388608 elems (u16)
  char* ws = (char*)d_ws;                   // needs ~42 MiB
  u16* Xb  = (u16*)ws;                      // dead after qkv
  u16* Ab  = Xb;                            // alias: attn output
  u16* VtG = (u16*)(ws + SEG * 2);          // V^T [bh][64][1024]
  u16* Wqt = (u16*)(ws + SEG * 4);
  u16* Wpt = Wqt + (size_t)3072 * 1024;
  u16* Qb  = (u16*)d_out;                   // d_out as scratch
  u16* Kb  = Qb + SEG;

  prep<<<5120, 256, 0, stream>>>(x, Xb, W_qkv, Wqt, W_prj, Wpt);
  qkv_gemm2<<<dim3(64, 24), 256, 0, stream>>>(Xb, Wqt, b_qkv, Qb, Kb, VtG);
  attn_kernel<<<dim3(128, 8), 256, 0, stream>>>(Qb, Kb, VtG, Ab);
  proj_gemm2<<<dim3(64, 8), 256, 0, stream>>>(Ab, Wpt, b_prj, out);
}